// Round 1
// baseline (147.864 us; speedup 1.0000x reference)
//
#include <hip/hip_runtime.h>
#include <hip/hip_bf16.h>
#include <math.h>

#define Bn 4
#define Nn 512
#define Dn 128
#define Hn 64
#define TT 4096                  // table resolution (nearest-neighbor lookup)
#define EPB 16
#define K0B ((TT + 1 + EPB - 1) / EPB)

__device__ __forceinline__ float silu_f(float x) {
    return x * (1.0f / (1.0f + __expf(-x)));
}

// ---------------------------------------------------------------------------
// k0: tabulate radial MLP G(x): scalar -> R^128 at x = e/TT.
// R13: wave-autonomous — hidden vectors live one-element-per-lane; GEMV
// broadcasts via __shfl (constant lane idx under full unroll -> readlane).
// No per-round __syncthreads, no h1/h2 LDS round-trip. EPB 8 -> 16 halves
// the number of blocks re-staging the 48 KB weight tiles.
// ---------------------------------------------------------------------------
struct K0S {
    float rW2s[Hn][Hn];
    float rW3s[Hn][Dn];
    float rW1s[Hn], rb1s[Hn], rg1s[Hn], rb2s[Hn], rg2s[Hn];
    float rb3s[Dn];
};

__global__ __launch_bounds__(256)
void k0_build_table(const float* __restrict__ rW1, const float* __restrict__ rb1,
                    const float* __restrict__ rg1,
                    const float* __restrict__ rW2, const float* __restrict__ rb2,
                    const float* __restrict__ rg2,
                    const float* __restrict__ rW3, const float* __restrict__ rb3,
                    __hip_bfloat16* __restrict__ table)
{
    __shared__ K0S sm;
    const int t  = threadIdx.x;
    const int k  = t & 63;
    const int wv = t >> 6;

    #pragma unroll
    for (int idx = t; idx < Hn * Hn; idx += 256)
        sm.rW2s[idx >> 6][idx & 63] = rW2[idx];
    #pragma unroll
    for (int idx = t; idx < Hn * Dn; idx += 256)
        sm.rW3s[idx >> 7][idx & 127] = rW3[idx];
    if (t < Hn) {
        sm.rW1s[t] = rW1[t];
        sm.rb1s[t] = rb1[t];
        sm.rg1s[t] = rg1[t];
        sm.rb2s[t] = rb2[t];
        sm.rg2s[t] = rg2[t];
    }
    if (t < Dn) sm.rb3s[t] = rb3[t];
    __syncthreads();                      // only barrier in the kernel

    const float w1v = sm.rW1s[k], b1v = sm.rb1s[k], g1v = sm.rg1s[k];
    const float b2v = sm.rb2s[k], g2v = sm.rg2s[k];

    for (int r = 0; r < EPB / 4; ++r) {
        const int e = blockIdx.x * EPB + r * 4 + wv;
        const float x = (float)e * (1.0f / (float)TT);

        float h = silu_f(x * w1v + b1v);
        float s1 = h, s2 = h * h;
        #pragma unroll
        for (int m = 1; m < 64; m <<= 1) { s1 += __shfl_xor(s1, m); s2 += __shfl_xor(s2, m); }
        float mean = s1 * (1.0f / 64.0f);
        float var  = s2 * (1.0f / 64.0f) - mean * mean;
        const float h1n = (h - mean) * rsqrtf(var + 1e-5f) * g1v;

        float p = 0.f;
        #pragma unroll
        for (int kk = 0; kk < Hn; ++kk)
            p += __shfl(h1n, kk) * sm.rW2s[kk][k];
        float h2 = silu_f(p + b2v);
        s1 = h2; s2 = h2 * h2;
        #pragma unroll
        for (int m = 1; m < 64; m <<= 1) { s1 += __shfl_xor(s1, m); s2 += __shfl_xor(s2, m); }
        mean = s1 * (1.0f / 64.0f);
        var  = s2 * (1.0f / 64.0f) - mean * mean;
        const float h2n = (h2 - mean) * rsqrtf(var + 1e-5f) * g2v;

        float f0 = sm.rb3s[k], f1 = sm.rb3s[64 + k];
        #pragma unroll
        for (int kk = 0; kk < Hn; ++kk) {
            const float hb = __shfl(h2n, kk);
            f0 += hb * sm.rW3s[kk][k];
            f1 += hb * sm.rW3s[kk][64 + k];
        }
        if (e <= TT) {
            table[e * Dn + k]      = __float2bfloat16(f0);
            table[e * Dn + 64 + k] = __float2bfloat16(f1);
        }
    }
}

// ---------------------------------------------------------------------------
// k1: fully fused.  Block = 4 rows (512 blocks); wave = one full row.
// R13 changes vs R12:
//   - contraction: 4-way entry split (s = lane>>4 strides 4 entries, 16
//     lanes x dwordx4 cover a full 256 B table row) -> 64 iterations/wave
//     instead of 128; cross-s reduce via 16 shfl_xor; accs LDS eliminated.
//   - epilogue: bias-reduce + LN stats + silu fused wave-per-row (all 256
//     lanes busy); final out reduce wave-per-row.  8 barriers -> 6.
//   - emb row hoisted to registers before compaction (latency overlap).
//   LDS 47.6 KB via union (ent dead before epilogue) -> 2 blocks/CU.
// ---------------------------------------------------------------------------
struct K1S {
    __hip_bfloat162 ntabS[100 * 64];       // 25.6 KB
    union {
        float2 ent[4][512];                // wave-private entry lists (16 KB)
        struct {
            float xs[4][256];              // 4 KB  [emb | nf] per row
            float pp[8][4][128];           // 16 KB GEMV partials [ch][row][out]
            float x2[4][128];              // 2 KB  post-LN/silu
        } epi;                             // 22 KB
    } u;
};

__global__ __launch_bounds__(256)
void k1_fused(const int* __restrict__ atoms, const float* __restrict__ rel,
              const int* __restrict__ adj, const int* __restrict__ mask,
              const float* __restrict__ soft, const float* __restrict__ ntab,
              const __hip_bfloat16* __restrict__ table,
              const float* __restrict__ atom_tab,
              const float* __restrict__ nW1, const float* __restrict__ nb1,
              const float* __restrict__ ng,
              const float* __restrict__ nW2, const float* __restrict__ nb2,
              float* __restrict__ out)
{
    __shared__ K1S sm;
    const int t    = threadIdx.x;
    const int lane = t & 63;
    const int wv   = t >> 6;
    const int bi0  = blockIdx.x * 4;       // first global row of this block
    const int b    = bi0 >> 9;             // batch (4 rows never straddle b)

    // ---- stage ntab -> LDS bf16 (once per 4 rows) ----
    for (int idx = t; idx < 100 * 64; idx += 256) {
        const float2 fv = ((const float2*)ntab)[idx];
        sm.ntabS[idx] = __hip_bfloat162(__float2bfloat16(fv.x), __float2bfloat16(fv.y));
    }

    // ---- wave-private ballot compaction: wave wv owns row bi0+wv ----
    const int ig      = bi0 + wv;          // global row index
    const int iloc    = ig & 511;          // i within batch
    const int rowbase = ig * Nn;
    const unsigned long long below = (1ull << lane) - 1ull;

    // hoisted embedding row (consumed only in the epilogue)
    const float2 embv = ((const float2*)&atom_tab[atoms[ig] * Dn])[lane];

    int cnt = 0;
    #pragma unroll
    for (int c = 0; c < 8; ++c) {
        const int j = c * 64 + lane;
        const float dist = rel[rowbase + j];
        const int   adjv = adj[rowbase + j];
        const int   mk   = mask[b * Nn + j];
        const float w = (adjv != 0 && mk != 0 && j != iloc) ? soft[rowbase + j] : 0.0f;
        int e = (int)(dist * (float)TT + 0.5f);
        e = min(max(e, 0), TT);
        const bool act = (w != 0.0f);
        const unsigned long long bm = __ballot(act);
        const int pre = __popcll(bm & below);
        if (act) sm.u.ent[wv][cnt + pre] =
            make_float2(w, __int_as_float(e | (atoms[b * Nn + j] << 16)));
        cnt += (int)__popcll(bm);
    }
    const int padded = (cnt + 7) & ~7;
    if (lane < padded - cnt)
        sm.u.ent[wv][cnt + lane] = make_float2(0.0f, __int_as_float(0));
    __syncthreads();    // B1: ntabS + ent visible

    // ---- contraction: 4-way entry split, 16 B table + 16 B ntab per step ----
    const int s  = lane >> 4;              // entry sub-stream 0..3
    const int dl = lane & 15;              // 16 lanes cover d = dl*8 .. dl*8+7
    const int d0 = dl * 8;
    float a0 = 0.f, a1 = 0.f, a2 = 0.f, a3 = 0.f;
    float a4 = 0.f, a5 = 0.f, a6 = 0.f, a7 = 0.f;
    #pragma unroll 8
    for (int n = s; n < padded; n += 4) {
        const float2 E  = sm.u.ent[wv][n];
        const float w   = E.x;
        const int  meta = __float_as_int(E.y);
        const int  e    = meta & 0xFFFF;
        const int  at   = meta >> 16;
        union { float4 f; __hip_bfloat162 h[4]; } T, Nv;
        T.f  = *(const float4*)&table[e * Dn + d0];          // dwordx4 gather
        Nv.f = *(const float4*)&sm.ntabS[at * 64 + dl * 4];  // ds_read_b128
        const float2 t0 = __bfloat1622float2(T.h[0]);
        const float2 t1 = __bfloat1622float2(T.h[1]);
        const float2 t2 = __bfloat1622float2(T.h[2]);
        const float2 t3 = __bfloat1622float2(T.h[3]);
        const float2 n0 = __bfloat1622float2(Nv.h[0]);
        const float2 n1 = __bfloat1622float2(Nv.h[1]);
        const float2 n2 = __bfloat1622float2(Nv.h[2]);
        const float2 n3 = __bfloat1622float2(Nv.h[3]);
        a0 += (w * n0.x) * t0.x;  a1 += (w * n0.y) * t0.y;
        a2 += (w * n1.x) * t1.x;  a3 += (w * n1.y) * t1.y;
        a4 += (w * n2.x) * t2.x;  a5 += (w * n2.y) * t2.y;
        a6 += (w * n3.x) * t3.x;  a7 += (w * n3.y) * t3.y;
    }
    // cross-s reduction: lanes {dl, dl+16, dl+32, dl+48} hold partials of
    // the same 8 d's -> butterfly over lane bits 4,5.
    a0 += __shfl_xor(a0, 16); a1 += __shfl_xor(a1, 16);
    a2 += __shfl_xor(a2, 16); a3 += __shfl_xor(a3, 16);
    a4 += __shfl_xor(a4, 16); a5 += __shfl_xor(a5, 16);
    a6 += __shfl_xor(a6, 16); a7 += __shfl_xor(a7, 16);
    a0 += __shfl_xor(a0, 32); a1 += __shfl_xor(a1, 32);
    a2 += __shfl_xor(a2, 32); a3 += __shfl_xor(a3, 32);
    a4 += __shfl_xor(a4, 32); a5 += __shfl_xor(a5, 32);
    a6 += __shfl_xor(a6, 32); a7 += __shfl_xor(a7, 32);
    __syncthreads();    // B2: all ent reads done (union flip to epi is safe)

    // ---- stage xs = [emb | nf] (wave-owned row, nf straight from regs) ----
    ((float2*)&sm.u.epi.xs[wv][0])[lane] = embv;
    if (lane < 16) {
        *(float4*)&sm.u.epi.xs[wv][Dn + d0]     = make_float4(a0, a1, a2, a3);
        *(float4*)&sm.u.epi.xs[wv][Dn + d0 + 4] = make_float4(a4, a5, a6, a7);
    }
    __syncthreads();    // B3

    const int og = t & 31;       // outputs 4*og .. 4*og+3
    const int ch = t >> 5;       // c-chunk 0..7

    // GEMV1: c-chunk of 32, weights reused across 4 rows
    {
        float acc[4][4];
        #pragma unroll
        for (int r = 0; r < 4; ++r)
            #pragma unroll
            for (int q = 0; q < 4; ++q) acc[r][q] = 0.f;
        const int c0 = ch * 32;
        #pragma unroll 8
        for (int c = 0; c < 32; ++c) {
            const float4 wv4 = *(const float4*)&nW1[(c0 + c) * Dn + og * 4];
            #pragma unroll
            for (int r = 0; r < 4; ++r) {
                const float xv = sm.u.epi.xs[r][c0 + c];
                acc[r][0] += xv * wv4.x; acc[r][1] += xv * wv4.y;
                acc[r][2] += xv * wv4.z; acc[r][3] += xv * wv4.w;
            }
        }
        #pragma unroll
        for (int r = 0; r < 4; ++r)
            *(float4*)&sm.u.epi.pp[ch][r][og * 4] =
                make_float4(acc[r][0], acc[r][1], acc[r][2], acc[r][3]);
    }
    __syncthreads();    // B4

    // fused bias + chunk-reduce + LN stats + silu: wave wv owns row wv
    {
        float lo = nb1[lane], hi = nb1[lane + 64];
        #pragma unroll
        for (int cc = 0; cc < 8; ++cc) {
            lo += sm.u.epi.pp[cc][wv][lane];
            hi += sm.u.epi.pp[cc][wv][lane + 64];
        }
        float s1 = lo + hi, s2 = lo * lo + hi * hi;
        #pragma unroll
        for (int m = 1; m < 64; m <<= 1) { s1 += __shfl_xor(s1, m); s2 += __shfl_xor(s2, m); }
        const float mean = s1 * (1.0f / 128.0f);
        const float var  = s2 * (1.0f / 128.0f) - mean * mean;
        const float rs   = rsqrtf(var + 1e-5f);
        sm.u.epi.x2[wv][lane]      = silu_f((lo - mean) * rs * ng[lane]);
        sm.u.epi.x2[wv][lane + 64] = silu_f((hi - mean) * rs * ng[lane + 64]);
    }
    __syncthreads();    // B5

    // GEMV2: c-chunk of 16
    {
        float acc[4][4];
        #pragma unroll
        for (int r = 0; r < 4; ++r)
            #pragma unroll
            for (int q = 0; q < 4; ++q) acc[r][q] = 0.f;
        const int c0 = ch * 16;
        #pragma unroll
        for (int c = 0; c < 16; ++c) {
            const float4 wv4 = *(const float4*)&nW2[(c0 + c) * Dn + og * 4];
            #pragma unroll
            for (int r = 0; r < 4; ++r) {
                const float xv = sm.u.epi.x2[r][c0 + c];
                acc[r][0] += xv * wv4.x; acc[r][1] += xv * wv4.y;
                acc[r][2] += xv * wv4.z; acc[r][3] += xv * wv4.w;
            }
        }
        #pragma unroll
        for (int r = 0; r < 4; ++r)
            *(float4*)&sm.u.epi.pp[ch][r][og * 4] =
                make_float4(acc[r][0], acc[r][1], acc[r][2], acc[r][3]);
    }
    __syncthreads();    // B6

    // final bias + chunk-reduce + store: wave wv owns row wv
    {
        float lo = nb2[lane], hi = nb2[lane + 64];
        #pragma unroll
        for (int cc = 0; cc < 8; ++cc) {
            lo += sm.u.epi.pp[cc][wv][lane];
            hi += sm.u.epi.pp[cc][wv][lane + 64];
        }
        out[(bi0 + wv) * Dn + lane]      = lo;
        out[(bi0 + wv) * Dn + lane + 64] = hi;
    }
}

// ---------------------------------------------------------------------------
extern "C" void kernel_launch(void* const* d_in, const int* in_sizes, int n_in,
                              void* d_out, int out_size, void* d_ws, size_t ws_size,
                              hipStream_t stream)
{
    (void)in_sizes; (void)n_in; (void)out_size; (void)ws_size;

    const int*   atoms = (const int*)d_in[0];
    const float* rel   = (const float*)d_in[1];
    const int*   adj   = (const int*)d_in[2];
    const int*   mask  = (const int*)d_in[3];
    const float* soft  = (const float*)d_in[4];
    const float* atab  = (const float*)d_in[5];
    const float* ntab  = (const float*)d_in[6];
    const float* rW1   = (const float*)d_in[7];
    const float* rb1   = (const float*)d_in[8];
    const float* rg1   = (const float*)d_in[9];
    const float* rW2   = (const float*)d_in[10];
    const float* rb2   = (const float*)d_in[11];
    const float* rg2   = (const float*)d_in[12];
    const float* rW3   = (const float*)d_in[13];
    const float* rb3   = (const float*)d_in[14];
    const float* nW1   = (const float*)d_in[15];
    const float* nb1   = (const float*)d_in[16];
    const float* ng    = (const float*)d_in[17];
    const float* nW2   = (const float*)d_in[18];
    const float* nb2   = (const float*)d_in[19];

    __hip_bfloat16* table = (__hip_bfloat16*)d_ws;   // (TT+1) x 128 bf16 ~ 1 MB
    float* out = (float*)d_out;

    hipLaunchKernelGGL(k0_build_table, dim3(K0B), dim3(256), 0, stream,
                       rW1, rb1, rg1, rW2, rb2, rg2, rW3, rb3, table);
    hipLaunchKernelGGL(k1_fused, dim3(Bn * Nn / 4), dim3(256), 0, stream,
                       atoms, rel, adj, mask, soft, ntab, table,
                       atab, nW1, nb1, ng, nW2, nb2, out);
}

// Round 2
// 147.203 us; speedup vs baseline: 1.0045x; 1.0045x over previous
//
#include <hip/hip_runtime.h>
#include <hip/hip_bf16.h>
#include <math.h>

#define Bn 4
#define Nn 512
#define Dn 128
#define Hn 64
#define TT 4096                  // table resolution (nearest-neighbor lookup)
#define EPB 8
#define K0B ((TT + 1 + EPB - 1) / EPB)

__device__ __forceinline__ float silu_f(float x) {
    return x * (1.0f / (1.0f + __expf(-x)));
}

// ---------------------------------------------------------------------------
// k0: tabulate radial MLP G(x): scalar -> R^128 at x = e/TT.
// R14: wave-autonomous (hidden vector one-element-per-lane, GEMV broadcast
// via __shfl with constant lane -> readlane; no h-buf LDS, no inner
// barriers), but back to EPB=8 / 513 blocks for 2-blocks/CU overlap
// (EPB=16's 257 blocks = 1/CU doubled the serial tail -> R13 regression).
// ---------------------------------------------------------------------------
struct K0S {
    float rW2s[Hn][Hn];
    float rW3s[Hn][Dn];
    float rW1s[Hn], rb1s[Hn], rg1s[Hn], rb2s[Hn], rg2s[Hn];
    float rb3s[Dn];
};

__global__ __launch_bounds__(256)
void k0_build_table(const float* __restrict__ rW1, const float* __restrict__ rb1,
                    const float* __restrict__ rg1,
                    const float* __restrict__ rW2, const float* __restrict__ rb2,
                    const float* __restrict__ rg2,
                    const float* __restrict__ rW3, const float* __restrict__ rb3,
                    __hip_bfloat16* __restrict__ table)
{
    __shared__ K0S sm;
    const int t  = threadIdx.x;
    const int k  = t & 63;
    const int wv = t >> 6;

    #pragma unroll
    for (int idx = t; idx < Hn * Hn; idx += 256)
        sm.rW2s[idx >> 6][idx & 63] = rW2[idx];
    #pragma unroll
    for (int idx = t; idx < Hn * Dn; idx += 256)
        sm.rW3s[idx >> 7][idx & 127] = rW3[idx];
    if (t < Hn) {
        sm.rW1s[t] = rW1[t];
        sm.rb1s[t] = rb1[t];
        sm.rg1s[t] = rg1[t];
        sm.rb2s[t] = rb2[t];
        sm.rg2s[t] = rg2[t];
    }
    if (t < Dn) sm.rb3s[t] = rb3[t];
    __syncthreads();                      // only barrier in the kernel

    const float w1v = sm.rW1s[k], b1v = sm.rb1s[k], g1v = sm.rg1s[k];
    const float b2v = sm.rb2s[k], g2v = sm.rg2s[k];

    for (int r = 0; r < EPB / 4; ++r) {
        const int e = blockIdx.x * EPB + r * 4 + wv;
        const float x = (float)e * (1.0f / (float)TT);

        float h = silu_f(x * w1v + b1v);
        float s1 = h, s2 = h * h;
        #pragma unroll
        for (int m = 1; m < 64; m <<= 1) { s1 += __shfl_xor(s1, m); s2 += __shfl_xor(s2, m); }
        float mean = s1 * (1.0f / 64.0f);
        float var  = s2 * (1.0f / 64.0f) - mean * mean;
        const float h1n = (h - mean) * rsqrtf(var + 1e-5f) * g1v;

        float p = 0.f;
        #pragma unroll
        for (int kk = 0; kk < Hn; ++kk)
            p += __shfl(h1n, kk) * sm.rW2s[kk][k];
        float h2 = silu_f(p + b2v);
        s1 = h2; s2 = h2 * h2;
        #pragma unroll
        for (int m = 1; m < 64; m <<= 1) { s1 += __shfl_xor(s1, m); s2 += __shfl_xor(s2, m); }
        mean = s1 * (1.0f / 64.0f);
        var  = s2 * (1.0f / 64.0f) - mean * mean;
        const float h2n = (h2 - mean) * rsqrtf(var + 1e-5f) * g2v;

        float f0 = sm.rb3s[k], f1 = sm.rb3s[64 + k];
        #pragma unroll
        for (int kk = 0; kk < Hn; ++kk) {
            const float hb = __shfl(h2n, kk);
            f0 += hb * sm.rW3s[kk][k];
            f1 += hb * sm.rW3s[kk][64 + k];
        }
        if (e <= TT) {
            table[e * Dn + k]      = __float2bfloat16(f0);
            table[e * Dn + 64 + k] = __float2bfloat16(f1);
        }
    }
}

// ---------------------------------------------------------------------------
// k1: fully fused.  Block = 4 rows (512 blocks); wave = one full row.
// R14 vs R12 (round-0) baseline:
//   - contraction: identical 2-way entry split / dwordx2 gather (known-good),
//     but cross-s reduce via 4x shfl_xor(32) -> accs LDS array + its barrier
//     and transpose round-trip eliminated.
//   - epilogue: bias-reduce + LN stats + silu fused wave-per-row (all 256
//     lanes busy); final out reduce wave-per-row.  8 barriers -> 6.
//   - emb row hoisted to registers before compaction (latency overlap).
//   LDS 47.0 KB -> 3 blocks/CU (was 53.8 KB / 2); __launch_bounds__(256,3)
//   caps VGPR at 170 so occupancy is LDS-limited, not register-limited.
// ---------------------------------------------------------------------------
struct K1S {
    __hip_bfloat162 ntabS[100 * 64];       // 25.6 KB
    union {
        float2 ent[4][512];                // wave-private entry lists (16 KB)
        struct {
            float xs[4][256];              // 4 KB  [emb | nf] per row
            float pp[8][4][128];           // 16 KB GEMV partials [ch][row][out]
            float x2[4][128];              // 2 KB  post-LN/silu
        } epi;                             // 22 KB
    } u;
};

__global__ __launch_bounds__(256, 3)
void k1_fused(const int* __restrict__ atoms, const float* __restrict__ rel,
              const int* __restrict__ adj, const int* __restrict__ mask,
              const float* __restrict__ soft, const float* __restrict__ ntab,
              const __hip_bfloat16* __restrict__ table,
              const float* __restrict__ atom_tab,
              const float* __restrict__ nW1, const float* __restrict__ nb1,
              const float* __restrict__ ng,
              const float* __restrict__ nW2, const float* __restrict__ nb2,
              float* __restrict__ out)
{
    __shared__ K1S sm;
    const int t    = threadIdx.x;
    const int lane = t & 63;
    const int wv   = t >> 6;
    const int bi0  = blockIdx.x * 4;       // first global row of this block
    const int b    = bi0 >> 9;             // batch (4 rows never straddle b)

    // ---- stage ntab -> LDS bf16 (once per 4 rows) ----
    for (int idx = t; idx < 100 * 64; idx += 256) {
        const float2 fv = ((const float2*)ntab)[idx];
        sm.ntabS[idx] = __hip_bfloat162(__float2bfloat16(fv.x), __float2bfloat16(fv.y));
    }

    // ---- wave-private ballot compaction: wave wv owns row bi0+wv ----
    const int ig      = bi0 + wv;          // global row index
    const int iloc    = ig & 511;          // i within batch
    const int rowbase = ig * Nn;
    const unsigned long long below = (1ull << lane) - 1ull;

    // hoisted embedding row (consumed only in the epilogue)
    const float2 embv = ((const float2*)&atom_tab[atoms[ig] * Dn])[lane];

    int cnt = 0;
    #pragma unroll
    for (int c = 0; c < 8; ++c) {
        const int j = c * 64 + lane;
        const float dist = rel[rowbase + j];
        const int   adjv = adj[rowbase + j];
        const int   mk   = mask[b * Nn + j];
        const float w = (adjv != 0 && mk != 0 && j != iloc) ? soft[rowbase + j] : 0.0f;
        int e = (int)(dist * (float)TT + 0.5f);
        e = min(max(e, 0), TT);
        const bool act = (w != 0.0f);
        const unsigned long long bm = __ballot(act);
        const int pre = __popcll(bm & below);
        if (act) sm.u.ent[wv][cnt + pre] =
            make_float2(w, __int_as_float(e | (atoms[b * Nn + j] << 16)));
        cnt += (int)__popcll(bm);
    }
    const int padded = (cnt + 7) & ~7;
    if (lane < padded - cnt)
        sm.u.ent[wv][cnt + lane] = make_float2(0.0f, __int_as_float(0));
    __syncthreads();    // B1: ntabS + ent visible

    // ---- contraction (round-0-verified): s strides entries, lane = 4 d ----
    const int s  = lane >> 5;
    const int dl = lane & 31;
    const int d0 = dl * 4;
    float a0 = 0.f, a1 = 0.f, a2 = 0.f, a3 = 0.f;
    #pragma unroll 8
    for (int n = s; n < padded; n += 2) {
        const float2 E  = sm.u.ent[wv][n];
        const float w   = E.x;
        const int  meta = __float_as_int(E.y);
        const int  e    = meta & 0xFFFF;
        const int  at   = meta >> 16;
        const __hip_bfloat162* tp = (const __hip_bfloat162*)&table[e * Dn + d0];
        const __hip_bfloat162 tva = tp[0], tvb = tp[1];
        const __hip_bfloat162 nva = sm.ntabS[at * 64 + dl * 2];
        const __hip_bfloat162 nvb = sm.ntabS[at * 64 + dl * 2 + 1];
        const float2 ta = __bfloat1622float2(tva);
        const float2 tb = __bfloat1622float2(tvb);
        const float2 na = __bfloat1622float2(nva);
        const float2 nb = __bfloat1622float2(nvb);
        a0 += (w * na.x) * ta.x;
        a1 += (w * na.y) * ta.y;
        a2 += (w * nb.x) * tb.x;
        a3 += (w * nb.y) * tb.y;
    }
    // cross-s reduction: lanes {dl, dl+32} hold partials of the same 4 d's.
    a0 += __shfl_xor(a0, 32);
    a1 += __shfl_xor(a1, 32);
    a2 += __shfl_xor(a2, 32);
    a3 += __shfl_xor(a3, 32);
    __syncthreads();    // B2: all ent reads done (union flip to epi is safe)

    // ---- stage xs = [emb | nf] (wave-owned row, nf straight from regs) ----
    ((float2*)&sm.u.epi.xs[wv][0])[lane] = embv;
    if (lane < 32)
        *(float4*)&sm.u.epi.xs[wv][Dn + d0] = make_float4(a0, a1, a2, a3);
    __syncthreads();    // B3

    const int og = t & 31;       // outputs 4*og .. 4*og+3
    const int ch = t >> 5;       // c-chunk 0..7

    // GEMV1: c-chunk of 32, weights reused across 4 rows
    {
        float acc[4][4];
        #pragma unroll
        for (int r = 0; r < 4; ++r)
            #pragma unroll
            for (int q = 0; q < 4; ++q) acc[r][q] = 0.f;
        const int c0 = ch * 32;
        #pragma unroll 8
        for (int c = 0; c < 32; ++c) {
            const float4 wv4 = *(const float4*)&nW1[(c0 + c) * Dn + og * 4];
            #pragma unroll
            for (int r = 0; r < 4; ++r) {
                const float xv = sm.u.epi.xs[r][c0 + c];
                acc[r][0] += xv * wv4.x; acc[r][1] += xv * wv4.y;
                acc[r][2] += xv * wv4.z; acc[r][3] += xv * wv4.w;
            }
        }
        #pragma unroll
        for (int r = 0; r < 4; ++r)
            *(float4*)&sm.u.epi.pp[ch][r][og * 4] =
                make_float4(acc[r][0], acc[r][1], acc[r][2], acc[r][3]);
    }
    __syncthreads();    // B4

    // fused bias + chunk-reduce + LN stats + silu: wave wv owns row wv
    {
        float lo = nb1[lane], hi = nb1[lane + 64];
        #pragma unroll
        for (int cc = 0; cc < 8; ++cc) {
            lo += sm.u.epi.pp[cc][wv][lane];
            hi += sm.u.epi.pp[cc][wv][lane + 64];
        }
        float s1 = lo + hi, s2 = lo * lo + hi * hi;
        #pragma unroll
        for (int m = 1; m < 64; m <<= 1) { s1 += __shfl_xor(s1, m); s2 += __shfl_xor(s2, m); }
        const float mean = s1 * (1.0f / 128.0f);
        const float var  = s2 * (1.0f / 128.0f) - mean * mean;
        const float rs   = rsqrtf(var + 1e-5f);
        sm.u.epi.x2[wv][lane]      = silu_f((lo - mean) * rs * ng[lane]);
        sm.u.epi.x2[wv][lane + 64] = silu_f((hi - mean) * rs * ng[lane + 64]);
    }
    __syncthreads();    // B5

    // GEMV2: c-chunk of 16
    {
        float acc[4][4];
        #pragma unroll
        for (int r = 0; r < 4; ++r)
            #pragma unroll
            for (int q = 0; q < 4; ++q) acc[r][q] = 0.f;
        const int c0 = ch * 16;
        #pragma unroll
        for (int c = 0; c < 16; ++c) {
            const float4 wv4 = *(const float4*)&nW2[(c0 + c) * Dn + og * 4];
            #pragma unroll
            for (int r = 0; r < 4; ++r) {
                const float xv = sm.u.epi.x2[r][c0 + c];
                acc[r][0] += xv * wv4.x; acc[r][1] += xv * wv4.y;
                acc[r][2] += xv * wv4.z; acc[r][3] += xv * wv4.w;
            }
        }
        #pragma unroll
        for (int r = 0; r < 4; ++r)
            *(float4*)&sm.u.epi.pp[ch][r][og * 4] =
                make_float4(acc[r][0], acc[r][1], acc[r][2], acc[r][3]);
    }
    __syncthreads();    // B6

    // final bias + chunk-reduce + store: wave wv owns row wv
    {
        float lo = nb2[lane], hi = nb2[lane + 64];
        #pragma unroll
        for (int cc = 0; cc < 8; ++cc) {
            lo += sm.u.epi.pp[cc][wv][lane];
            hi += sm.u.epi.pp[cc][wv][lane + 64];
        }
        out[(bi0 + wv) * Dn + lane]      = lo;
        out[(bi0 + wv) * Dn + lane + 64] = hi;
    }
}

// ---------------------------------------------------------------------------
extern "C" void kernel_launch(void* const* d_in, const int* in_sizes, int n_in,
                              void* d_out, int out_size, void* d_ws, size_t ws_size,
                              hipStream_t stream)
{
    (void)in_sizes; (void)n_in; (void)out_size; (void)ws_size;

    const int*   atoms = (const int*)d_in[0];
    const float* rel   = (const float*)d_in[1];
    const int*   adj   = (const int*)d_in[2];
    const int*   mask  = (const int*)d_in[3];
    const float* soft  = (const float*)d_in[4];
    const float* atab  = (const float*)d_in[5];
    const float* ntab  = (const float*)d_in[6];
    const float* rW1   = (const float*)d_in[7];
    const float* rb1   = (const float*)d_in[8];
    const float* rg1   = (const float*)d_in[9];
    const float* rW2   = (const float*)d_in[10];
    const float* rb2   = (const float*)d_in[11];
    const float* rg2   = (const float*)d_in[12];
    const float* rW3   = (const float*)d_in[13];
    const float* rb3   = (const float*)d_in[14];
    const float* nW1   = (const float*)d_in[15];
    const float* nb1   = (const float*)d_in[16];
    const float* ng    = (const float*)d_in[17];
    const float* nW2   = (const float*)d_in[18];
    const float* nb2   = (const float*)d_in[19];

    __hip_bfloat16* table = (__hip_bfloat16*)d_ws;   // (TT+1) x 128 bf16 ~ 1 MB
    float* out = (float*)d_out;

    hipLaunchKernelGGL(k0_build_table, dim3(K0B), dim3(256), 0, stream,
                       rW1, rb1, rg1, rW2, rb2, rg2, rW3, rb3, table);
    hipLaunchKernelGGL(k1_fused, dim3(Bn * Nn / 4), dim3(256), 0, stream,
                       atoms, rel, adj, mask, soft, ntab, table,
                       atab, nW1, nb1, ng, nW2, nb2, out);
}

// Round 3
// 135.377 us; speedup vs baseline: 1.0922x; 1.0874x over previous
//
#include <hip/hip_runtime.h>
#include <hip/hip_bf16.h>
#include <math.h>

#define Bn 4
#define Nn 512
#define Dn 128
#define Hn 64
#define TT 4096                  // table resolution (nearest-neighbor lookup)
#define EPB 8
#define K0B ((TT + 1 + EPB - 1) / EPB)

__device__ __forceinline__ float silu_f(float x) {
    return x * (1.0f / (1.0f + __expf(-x)));
}

// ---------------------------------------------------------------------------
// k0: tabulate radial MLP G(x): scalar -> R^128 at x = e/TT.
// R15: back to round-0's LDS h-buf broadcast GEMVs (R13/R14's __shfl form
// lowers to ds_bpermute with per-lane addr setup + lgkmcnt round-trips --
// the prime suspect for the R13/R14 regression). h1buf/h2buf are
// wave-private, so the per-round __syncthreads of round 0 are dropped:
// same-wave DS ordering via lgkmcnt is sufficient.
// ---------------------------------------------------------------------------
struct K0S {
    float rW2s[Hn][Hn];
    float rW3s[Hn][Dn];
    float rW1s[Hn], rb1s[Hn], rg1s[Hn], rb2s[Hn], rg2s[Hn];
    float rb3s[Dn];
    float h1buf[4][Hn];
    float h2buf[4][Hn];
};

__global__ __launch_bounds__(256)
void k0_build_table(const float* __restrict__ rW1, const float* __restrict__ rb1,
                    const float* __restrict__ rg1,
                    const float* __restrict__ rW2, const float* __restrict__ rb2,
                    const float* __restrict__ rg2,
                    const float* __restrict__ rW3, const float* __restrict__ rb3,
                    __hip_bfloat16* __restrict__ table)
{
    __shared__ K0S sm;
    const int t  = threadIdx.x;
    const int k  = t & 63;
    const int wv = t >> 6;

    #pragma unroll
    for (int idx = t; idx < Hn * Hn; idx += 256)
        sm.rW2s[idx >> 6][idx & 63] = rW2[idx];
    #pragma unroll
    for (int idx = t; idx < Hn * Dn; idx += 256)
        sm.rW3s[idx >> 7][idx & 127] = rW3[idx];
    if (t < Hn) {
        sm.rW1s[t] = rW1[t];
        sm.rb1s[t] = rb1[t];
        sm.rg1s[t] = rg1[t];
        sm.rb2s[t] = rb2[t];
        sm.rg2s[t] = rg2[t];
    }
    if (t < Dn) sm.rb3s[t] = rb3[t];
    __syncthreads();                      // only barrier in the kernel

    const float w1v = sm.rW1s[k], b1v = sm.rb1s[k], g1v = sm.rg1s[k];
    const float b2v = sm.rb2s[k], g2v = sm.rg2s[k];

    for (int r = 0; r < EPB / 4; ++r) {
        const int e = blockIdx.x * EPB + r * 4 + wv;
        const float x = (float)e * (1.0f / (float)TT);

        float h = silu_f(x * w1v + b1v);
        float s1 = h, s2 = h * h;
        #pragma unroll
        for (int m = 1; m < 64; m <<= 1) { s1 += __shfl_xor(s1, m); s2 += __shfl_xor(s2, m); }
        float mean = s1 * (1.0f / 64.0f);
        float var  = s2 * (1.0f / 64.0f) - mean * mean;
        float rs   = rsqrtf(var + 1e-5f);
        sm.h1buf[wv][k] = (h - mean) * rs * g1v;
        // wave-private buffer: same-wave DS ordering (lgkmcnt) suffices,
        // no __syncthreads needed.

        float p = 0.f;
        #pragma unroll 8
        for (int kk = 0; kk < Hn; ++kk)
            p += sm.h1buf[wv][kk] * sm.rW2s[kk][k];
        float h2 = silu_f(p + b2v);
        s1 = h2; s2 = h2 * h2;
        #pragma unroll
        for (int m = 1; m < 64; m <<= 1) { s1 += __shfl_xor(s1, m); s2 += __shfl_xor(s2, m); }
        mean = s1 * (1.0f / 64.0f);
        var  = s2 * (1.0f / 64.0f) - mean * mean;
        rs   = rsqrtf(var + 1e-5f);
        sm.h2buf[wv][k] = (h2 - mean) * rs * g2v;

        #pragma unroll
        for (int dd = 0; dd < 2; ++dd) {
            const int d = dd * 64 + k;
            float f = sm.rb3s[d];
            #pragma unroll 8
            for (int kk = 0; kk < Hn; ++kk)
                f += sm.h2buf[wv][kk] * sm.rW3s[kk][d];
            if (e <= TT) table[e * Dn + d] = __float2bfloat16(f);
        }
    }
}

// ---------------------------------------------------------------------------
// k1: fully fused.  Block = 4 rows (512 blocks); wave = one full row.
// R15 = R14 (mechanism-clean set kept):
//   - contraction: round-0-verified 2-way entry split / dwordx2 gather;
//     cross-s reduce via 4x shfl_xor(32) -> accs LDS + barrier eliminated.
//   - epilogue: bias-reduce + LN stats + silu fused wave-per-row (all 256
//     lanes busy); final out reduce wave-per-row.  8 barriers -> 6.
//   - emb row hoisted to registers before compaction (latency overlap).
//   - plain __launch_bounds__(256): no VGPR cap (spill risk removed);
//     LDS 47.0 KB.
// ---------------------------------------------------------------------------
struct K1S {
    __hip_bfloat162 ntabS[100 * 64];       // 25.6 KB
    union {
        float2 ent[4][512];                // wave-private entry lists (16 KB)
        struct {
            float xs[4][256];              // 4 KB  [emb | nf] per row
            float pp[8][4][128];           // 16 KB GEMV partials [ch][row][out]
            float x2[4][128];              // 2 KB  post-LN/silu
        } epi;                             // 22 KB
    } u;
};

__global__ __launch_bounds__(256)
void k1_fused(const int* __restrict__ atoms, const float* __restrict__ rel,
              const int* __restrict__ adj, const int* __restrict__ mask,
              const float* __restrict__ soft, const float* __restrict__ ntab,
              const __hip_bfloat16* __restrict__ table,
              const float* __restrict__ atom_tab,
              const float* __restrict__ nW1, const float* __restrict__ nb1,
              const float* __restrict__ ng,
              const float* __restrict__ nW2, const float* __restrict__ nb2,
              float* __restrict__ out)
{
    __shared__ K1S sm;
    const int t    = threadIdx.x;
    const int lane = t & 63;
    const int wv   = t >> 6;
    const int bi0  = blockIdx.x * 4;       // first global row of this block
    const int b    = bi0 >> 9;             // batch (4 rows never straddle b)

    // ---- stage ntab -> LDS bf16 (once per 4 rows) ----
    for (int idx = t; idx < 100 * 64; idx += 256) {
        const float2 fv = ((const float2*)ntab)[idx];
        sm.ntabS[idx] = __hip_bfloat162(__float2bfloat16(fv.x), __float2bfloat16(fv.y));
    }

    // ---- wave-private ballot compaction: wave wv owns row bi0+wv ----
    const int ig      = bi0 + wv;          // global row index
    const int iloc    = ig & 511;          // i within batch
    const int rowbase = ig * Nn;
    const unsigned long long below = (1ull << lane) - 1ull;

    // hoisted embedding row (consumed only in the epilogue)
    const float2 embv = ((const float2*)&atom_tab[atoms[ig] * Dn])[lane];

    int cnt = 0;
    #pragma unroll
    for (int c = 0; c < 8; ++c) {
        const int j = c * 64 + lane;
        const float dist = rel[rowbase + j];
        const int   adjv = adj[rowbase + j];
        const int   mk   = mask[b * Nn + j];
        const float w = (adjv != 0 && mk != 0 && j != iloc) ? soft[rowbase + j] : 0.0f;
        int e = (int)(dist * (float)TT + 0.5f);
        e = min(max(e, 0), TT);
        const bool act = (w != 0.0f);
        const unsigned long long bm = __ballot(act);
        const int pre = __popcll(bm & below);
        if (act) sm.u.ent[wv][cnt + pre] =
            make_float2(w, __int_as_float(e | (atoms[b * Nn + j] << 16)));
        cnt += (int)__popcll(bm);
    }
    const int padded = (cnt + 7) & ~7;
    if (lane < padded - cnt)
        sm.u.ent[wv][cnt + lane] = make_float2(0.0f, __int_as_float(0));
    __syncthreads();    // B1: ntabS + ent visible

    // ---- contraction (round-0-verified): s strides entries, lane = 4 d ----
    const int s  = lane >> 5;
    const int dl = lane & 31;
    const int d0 = dl * 4;
    float a0 = 0.f, a1 = 0.f, a2 = 0.f, a3 = 0.f;
    #pragma unroll 8
    for (int n = s; n < padded; n += 2) {
        const float2 E  = sm.u.ent[wv][n];
        const float w   = E.x;
        const int  meta = __float_as_int(E.y);
        const int  e    = meta & 0xFFFF;
        const int  at   = meta >> 16;
        const __hip_bfloat162* tp = (const __hip_bfloat162*)&table[e * Dn + d0];
        const __hip_bfloat162 tva = tp[0], tvb = tp[1];
        const __hip_bfloat162 nva = sm.ntabS[at * 64 + dl * 2];
        const __hip_bfloat162 nvb = sm.ntabS[at * 64 + dl * 2 + 1];
        const float2 ta = __bfloat1622float2(tva);
        const float2 tb = __bfloat1622float2(tvb);
        const float2 na = __bfloat1622float2(nva);
        const float2 nb = __bfloat1622float2(nvb);
        a0 += (w * na.x) * ta.x;
        a1 += (w * na.y) * ta.y;
        a2 += (w * nb.x) * tb.x;
        a3 += (w * nb.y) * tb.y;
    }
    // cross-s reduction: lanes {dl, dl+32} hold partials of the same 4 d's.
    a0 += __shfl_xor(a0, 32);
    a1 += __shfl_xor(a1, 32);
    a2 += __shfl_xor(a2, 32);
    a3 += __shfl_xor(a3, 32);
    __syncthreads();    // B2: all ent reads done (union flip to epi is safe)

    // ---- stage xs = [emb | nf] (wave-owned row, nf straight from regs) ----
    ((float2*)&sm.u.epi.xs[wv][0])[lane] = embv;
    if (lane < 32)
        *(float4*)&sm.u.epi.xs[wv][Dn + d0] = make_float4(a0, a1, a2, a3);
    __syncthreads();    // B3

    const int og = t & 31;       // outputs 4*og .. 4*og+3
    const int ch = t >> 5;       // c-chunk 0..7

    // GEMV1: c-chunk of 32, weights reused across 4 rows
    {
        float acc[4][4];
        #pragma unroll
        for (int r = 0; r < 4; ++r)
            #pragma unroll
            for (int q = 0; q < 4; ++q) acc[r][q] = 0.f;
        const int c0 = ch * 32;
        #pragma unroll 8
        for (int c = 0; c < 32; ++c) {
            const float4 wv4 = *(const float4*)&nW1[(c0 + c) * Dn + og * 4];
            #pragma unroll
            for (int r = 0; r < 4; ++r) {
                const float xv = sm.u.epi.xs[r][c0 + c];
                acc[r][0] += xv * wv4.x; acc[r][1] += xv * wv4.y;
                acc[r][2] += xv * wv4.z; acc[r][3] += xv * wv4.w;
            }
        }
        #pragma unroll
        for (int r = 0; r < 4; ++r)
            *(float4*)&sm.u.epi.pp[ch][r][og * 4] =
                make_float4(acc[r][0], acc[r][1], acc[r][2], acc[r][3]);
    }
    __syncthreads();    // B4

    // fused bias + chunk-reduce + LN stats + silu: wave wv owns row wv
    {
        float lo = nb1[lane], hi = nb1[lane + 64];
        #pragma unroll
        for (int cc = 0; cc < 8; ++cc) {
            lo += sm.u.epi.pp[cc][wv][lane];
            hi += sm.u.epi.pp[cc][wv][lane + 64];
        }
        float s1 = lo + hi, s2 = lo * lo + hi * hi;
        #pragma unroll
        for (int m = 1; m < 64; m <<= 1) { s1 += __shfl_xor(s1, m); s2 += __shfl_xor(s2, m); }
        const float mean = s1 * (1.0f / 128.0f);
        const float var  = s2 * (1.0f / 128.0f) - mean * mean;
        const float rs   = rsqrtf(var + 1e-5f);
        sm.u.epi.x2[wv][lane]      = silu_f((lo - mean) * rs * ng[lane]);
        sm.u.epi.x2[wv][lane + 64] = silu_f((hi - mean) * rs * ng[lane + 64]);
    }
    __syncthreads();    // B5

    // GEMV2: c-chunk of 16
    {
        float acc[4][4];
        #pragma unroll
        for (int r = 0; r < 4; ++r)
            #pragma unroll
            for (int q = 0; q < 4; ++q) acc[r][q] = 0.f;
        const int c0 = ch * 16;
        #pragma unroll
        for (int c = 0; c < 16; ++c) {
            const float4 wv4 = *(const float4*)&nW2[(c0 + c) * Dn + og * 4];
            #pragma unroll
            for (int r = 0; r < 4; ++r) {
                const float xv = sm.u.epi.x2[r][c0 + c];
                acc[r][0] += xv * wv4.x; acc[r][1] += xv * wv4.y;
                acc[r][2] += xv * wv4.z; acc[r][3] += xv * wv4.w;
            }
        }
        #pragma unroll
        for (int r = 0; r < 4; ++r)
            *(float4*)&sm.u.epi.pp[ch][r][og * 4] =
                make_float4(acc[r][0], acc[r][1], acc[r][2], acc[r][3]);
    }
    __syncthreads();    // B6

    // final bias + chunk-reduce + store: wave wv owns row wv
    {
        float lo = nb2[lane], hi = nb2[lane + 64];
        #pragma unroll
        for (int cc = 0; cc < 8; ++cc) {
            lo += sm.u.epi.pp[cc][wv][lane];
            hi += sm.u.epi.pp[cc][wv][lane + 64];
        }
        out[(bi0 + wv) * Dn + lane]      = lo;
        out[(bi0 + wv) * Dn + lane + 64] = hi;
    }
}

// ---------------------------------------------------------------------------
extern "C" void kernel_launch(void* const* d_in, const int* in_sizes, int n_in,
                              void* d_out, int out_size, void* d_ws, size_t ws_size,
                              hipStream_t stream)
{
    (void)in_sizes; (void)n_in; (void)out_size; (void)ws_size;

    const int*   atoms = (const int*)d_in[0];
    const float* rel   = (const float*)d_in[1];
    const int*   adj   = (const int*)d_in[2];
    const int*   mask  = (const int*)d_in[3];
    const float* soft  = (const float*)d_in[4];
    const float* atab  = (const float*)d_in[5];
    const float* ntab  = (const float*)d_in[6];
    const float* rW1   = (const float*)d_in[7];
    const float* rb1   = (const float*)d_in[8];
    const float* rg1   = (const float*)d_in[9];
    const float* rW2   = (const float*)d_in[10];
    const float* rb2   = (const float*)d_in[11];
    const float* rg2   = (const float*)d_in[12];
    const float* rW3   = (const float*)d_in[13];
    const float* rb3   = (const float*)d_in[14];
    const float* nW1   = (const float*)d_in[15];
    const float* nb1   = (const float*)d_in[16];
    const float* ng    = (const float*)d_in[17];
    const float* nW2   = (const float*)d_in[18];
    const float* nb2   = (const float*)d_in[19];

    __hip_bfloat16* table = (__hip_bfloat16*)d_ws;   // (TT+1) x 128 bf16 ~ 1 MB
    float* out = (float*)d_out;

    hipLaunchKernelGGL(k0_build_table, dim3(K0B), dim3(256), 0, stream,
                       rW1, rb1, rg1, rW2, rb2, rg2, rW3, rb3, table);
    hipLaunchKernelGGL(k1_fused, dim3(Bn * Nn / 4), dim3(256), 0, stream,
                       atoms, rel, adj, mask, soft, ntab, table,
                       atab, nW1, nb1, ng, nW2, nb2, out);
}